// Round 12
// baseline (210.111 us; speedup 1.0000x reference)
//
#include <hip/hip_runtime.h>
#include <hip/hip_bf16.h>

typedef __bf16 bf16x8 __attribute__((ext_vector_type(8)));
typedef float f32x4 __attribute__((ext_vector_type(4)));

#define EPS 1e-5f
// 0.125 * log2(e): folded into Q via LN gamma/beta in qkv, so P = exp2(S)
#define QSCALE 0.18033688011112042f

__device__ __forceinline__ unsigned short f2bf(float f) {
  union { float f; unsigned int i; } c; c.f = f;
  unsigned int r = c.i + 0x7FFFu + ((c.i >> 16) & 1u);
  return (unsigned short)(r >> 16);
}
// truncating fp32->bf16 (for P>=0: <=1ulp, saves the rounding chain)
__device__ __forceinline__ unsigned short f2bf_t(float f) {
  union { float f; unsigned int i; } c; c.f = f;
  return (unsigned short)(c.i >> 16);
}

// async global->LDS DMA, 16B per lane. LDS dest must be wave-uniform base
// (HW writes base + lane*16); global src is per-lane.
__device__ __forceinline__ void glds16(const void* g, void* l) {
  __builtin_amdgcn_global_load_lds(
      (const __attribute__((address_space(1))) unsigned int*)g,
      (__attribute__((address_space(3))) unsigned int*)l, 16, 0, 0);
}

// ---------------- Prep: both weight transposes + optional X convert -------
__device__ __forceinline__ void transpose_tile(
    const float* __restrict__ in, unsigned short* __restrict__ out,
    int R, int C, int ct0, int rt0, unsigned short* S /*64*72*/)
{
  const int t = threadIdx.x;
  const int r = t >> 2, c4 = (t & 3) * 16;
  {
    long base = (long)(rt0 + r) * C + ct0 + c4;
    float4 a = *(const float4*)&in[base];
    float4 b = *(const float4*)&in[base + 4];
    float4 c = *(const float4*)&in[base + 8];
    float4 d = *(const float4*)&in[base + 12];
    unsigned short v[16] = {f2bf(a.x), f2bf(a.y), f2bf(a.z), f2bf(a.w),
                            f2bf(b.x), f2bf(b.y), f2bf(b.z), f2bf(b.w),
                            f2bf(c.x), f2bf(c.y), f2bf(c.z), f2bf(c.w),
                            f2bf(d.x), f2bf(d.y), f2bf(d.z), f2bf(d.w)};
    *(uint4*)&S[r * 72 + c4]     = *(uint4*)&v[0];
    *(uint4*)&S[r * 72 + c4 + 8] = *(uint4*)&v[8];
  }
  __syncthreads();
  unsigned short tmp[16];
#pragma unroll
  for (int j = 0; j < 16; j++) tmp[j] = S[(c4 + j) * 72 + r];
  *(uint4*)&out[(long)(ct0 + r) * R + rt0 + c4]     = *(uint4*)&tmp[0];
  *(uint4*)&out[(long)(ct0 + r) * R + rt0 + c4 + 8] = *(uint4*)&tmp[8];
}

__global__ __launch_bounds__(256) void prep_kernel(
    const float* __restrict__ Wa, const float* __restrict__ Wp,
    const float* __restrict__ X,
    unsigned short* __restrict__ WaT, unsigned short* __restrict__ WpT,
    unsigned short* __restrict__ Xbf)
{
  __shared__ __align__(16) unsigned short S[64 * 72];
  const int id = blockIdx.x;
  if (id < 768) {                    // Wa [1024,3072] -> WaT [3072,1024]
    transpose_tile(Wa, WaT, 1024, 3072, (id % 48) * 64, (id / 48) * 64, S);
  } else if (id < 1024) {            // Wp [1024,1024] -> WpT [1024,1024]
    const int i2 = id - 768;
    transpose_tile(Wp, WpT, 1024, 1024, (i2 % 16) * 64, (i2 / 16) * 64, S);
  } else {                           // X fp32 -> bf16 (big-ws only)
    long i = ((long)(id - 1024) * 256 + threadIdx.x) * 16;
    float4 a = *(const float4*)&X[i];
    float4 b = *(const float4*)&X[i + 4];
    float4 c = *(const float4*)&X[i + 8];
    float4 d = *(const float4*)&X[i + 12];
    unsigned short v[16] = {f2bf(a.x), f2bf(a.y), f2bf(a.z), f2bf(a.w),
                            f2bf(b.x), f2bf(b.y), f2bf(b.z), f2bf(b.w),
                            f2bf(c.x), f2bf(c.y), f2bf(c.z), f2bf(c.w),
                            f2bf(d.x), f2bf(d.y), f2bf(d.z), f2bf(d.w)};
    *(uint4*)&Xbf[i]     = *(uint4*)&v[0];
    *(uint4*)&Xbf[i + 8] = *(uint4*)&v[8];
  }
}

// ---------- Merged GEMM: blocks 0..511 Q/K+LN, 512..1023 V^T --------------
// bf16 path: glds16 into 2-buffer LDS (r1-proven best: 58us, 4 blk/CU).
__global__ __launch_bounds__(256) void qkvt_kernel(
    const float* __restrict__ Xf,
    const unsigned short* __restrict__ Xbf, int use_xbf,
    const unsigned short* __restrict__ WT,    // WaT [3072,1024]
    const float* __restrict__ bias,           // b_attn [3072]
    const float* __restrict__ qg, const float* __restrict__ qb,
    const float* __restrict__ kg, const float* __restrict__ kb,
    unsigned short* __restrict__ Qws, unsigned short* __restrict__ Kws,
    unsigned short* __restrict__ Vt)
{
  __shared__ __align__(16) unsigned short As[2][128 * 32];
  __shared__ __align__(16) unsigned short Bs[2][128 * 32];

  const int tid = threadIdx.x;
  const int w = tid >> 6, lane = tid & 63, quad = lane >> 4, l15 = lane & 15;
  const int mh = w & 1, nh = w >> 1;
  const int id = blockIdx.x;
  // glds addressing: each wave stages contiguous 16-row groups; lane covers
  // row (lane>>2) of the group, 16B column chunk (lane&3).
  const int grow = lane >> 2, gcol = (lane & 3) * 8;

  if (id < 512) {
    // ---------------- Q/K GEMM 128x128 + QK-LN ----------------
    const int n0 = (id & 15) * 128, m0 = (id >> 4) * 128;

    f32x4 acc[4][4];
#pragma unroll
    for (int i = 0; i < 4; i++)
#pragma unroll
      for (int j = 0; j < 4; j++) acc[i][j] = (f32x4){0.f, 0.f, 0.f, 0.f};

    if (use_xbf) {
      const long ga = (long)(m0 + w * 32 + grow) * 1024 + gcol;
      const long gb = (long)(n0 + w * 32 + grow) * 1024 + gcol;
#define STAGE_QK(bf, kk) do { \
        glds16(&Xbf[ga + (kk)],             &As[bf][(w * 32) * 32]); \
        glds16(&Xbf[ga + (kk) + 16 * 1024], &As[bf][(w * 32 + 16) * 32]); \
        glds16(&WT[gb + (kk)],              &Bs[bf][(w * 32) * 32]); \
        glds16(&WT[gb + (kk) + 16 * 1024],  &Bs[bf][(w * 32 + 16) * 32]); \
      } while (0)
      STAGE_QK(0, 0);
      __syncthreads();
      int buf = 0;
      for (int kt = 0; kt < 1024; kt += 32) {
        if (kt + 32 < 1024) STAGE_QK(buf ^ 1, kt + 32);
        bf16x8 af[4], bfr[4];
#pragma unroll
        for (int mq = 0; mq < 4; mq++)
          af[mq] = *(const bf16x8*)&As[buf][(mh * 64 + mq * 16 + l15) * 32 + quad * 8];
#pragma unroll
        for (int nq = 0; nq < 4; nq++)
          bfr[nq] = *(const bf16x8*)&Bs[buf][(nh * 64 + nq * 16 + l15) * 32 + quad * 8];
#pragma unroll
        for (int mq = 0; mq < 4; mq++)
#pragma unroll
          for (int nq = 0; nq < 4; nq++)
            acc[mq][nq] = __builtin_amdgcn_mfma_f32_16x16x32_bf16(af[mq], bfr[nq], acc[mq][nq], 0, 0, 0);
        __syncthreads();
        buf ^= 1;
      }
#undef STAGE_QK
    } else {
      // -------- fp32-X fallback: reg-staged double buffer ------
      const int sr2 = tid >> 1, sh2 = (tid & 1) * 16;
      {
        long xo = (long)(m0 + sr2) * 1024 + sh2;
        float4 a0 = *(const float4*)&Xf[xo];
        float4 a1 = *(const float4*)&Xf[xo + 4];
        float4 a2 = *(const float4*)&Xf[xo + 8];
        float4 a3 = *(const float4*)&Xf[xo + 12];
        unsigned short v[16] = {f2bf(a0.x), f2bf(a0.y), f2bf(a0.z), f2bf(a0.w),
                                f2bf(a1.x), f2bf(a1.y), f2bf(a1.z), f2bf(a1.w),
                                f2bf(a2.x), f2bf(a2.y), f2bf(a2.z), f2bf(a2.w),
                                f2bf(a3.x), f2bf(a3.y), f2bf(a3.z), f2bf(a3.w)};
        *(uint4*)&As[0][sr2 * 32 + sh2]     = *(uint4*)&v[0];
        *(uint4*)&As[0][sr2 * 32 + sh2 + 8] = *(uint4*)&v[8];
        long wo = (long)(n0 + sr2) * 1024 + sh2;
        *(uint4*)&Bs[0][sr2 * 32 + sh2]     = *(const uint4*)&WT[wo];
        *(uint4*)&Bs[0][sr2 * 32 + sh2 + 8] = *(const uint4*)&WT[wo + 8];
      }
      __syncthreads();

      int buf = 0;
      for (int kt = 0; kt < 1024; kt += 32) {
        const int nbuf = buf ^ 1;
        const bool pf = (kt + 32) < 1024;
        uint4 wv0, wv1;
        float4 a0, a1, a2, a3;
        if (pf) {
          long xo = (long)(m0 + sr2) * 1024 + kt + 32 + sh2;
          a0 = *(const float4*)&Xf[xo];
          a1 = *(const float4*)&Xf[xo + 4];
          a2 = *(const float4*)&Xf[xo + 8];
          a3 = *(const float4*)&Xf[xo + 12];
          long wo = (long)(n0 + sr2) * 1024 + kt + 32 + sh2;
          wv0 = *(const uint4*)&WT[wo];
          wv1 = *(const uint4*)&WT[wo + 8];
        }

        bf16x8 af[4], bfr[4];
#pragma unroll
        for (int mq = 0; mq < 4; mq++)
          af[mq] = *(const bf16x8*)&As[buf][(mh * 64 + mq * 16 + l15) * 32 + quad * 8];
#pragma unroll
        for (int nq = 0; nq < 4; nq++)
          bfr[nq] = *(const bf16x8*)&Bs[buf][(nh * 64 + nq * 16 + l15) * 32 + quad * 8];
#pragma unroll
        for (int mq = 0; mq < 4; mq++)
#pragma unroll
          for (int nq = 0; nq < 4; nq++)
            acc[mq][nq] = __builtin_amdgcn_mfma_f32_16x16x32_bf16(af[mq], bfr[nq], acc[mq][nq], 0, 0, 0);

        if (pf) {
          unsigned short v[16] = {f2bf(a0.x), f2bf(a0.y), f2bf(a0.z), f2bf(a0.w),
                                  f2bf(a1.x), f2bf(a1.y), f2bf(a1.z), f2bf(a1.w),
                                  f2bf(a2.x), f2bf(a2.y), f2bf(a2.z), f2bf(a2.w),
                                  f2bf(a3.x), f2bf(a3.y), f2bf(a3.z), f2bf(a3.w)};
          *(uint4*)&As[nbuf][sr2 * 32 + sh2]     = *(uint4*)&v[0];
          *(uint4*)&As[nbuf][sr2 * 32 + sh2 + 8] = *(uint4*)&v[8];
          *(uint4*)&Bs[nbuf][sr2 * 32 + sh2]     = wv0;
          *(uint4*)&Bs[nbuf][sr2 * 32 + sh2 + 8] = wv1;
        }
        __syncthreads();
        buf = nbuf;
      }
    }

#pragma unroll
    for (int nq = 0; nq < 4; nq++) {
      float bv = bias[n0 + nh * 64 + nq * 16 + l15];
#pragma unroll
      for (int mq = 0; mq < 4; mq++)
#pragma unroll
        for (int rr = 0; rr < 4; rr++) acc[mq][nq][rr] += bv;
    }

    const int g = (n0 >> 6) + nh;   // 0..31: Q heads then K heads
    const bool isQ = g < 16;
    {
      float gv[4], bev[4];
#pragma unroll
      for (int nq = 0; nq < 4; nq++) {
        int d = nq * 16 + l15;
        gv[nq]  = isQ ? qg[d] : kg[d];
        bev[nq] = isQ ? qb[d] : kb[d];
        if (isQ) { gv[nq] *= QSCALE; bev[nq] *= QSCALE; }
      }
#pragma unroll
      for (int mq = 0; mq < 4; mq++)
#pragma unroll
        for (int rr = 0; rr < 4; rr++) {
          float s  = acc[mq][0][rr] + acc[mq][1][rr] + acc[mq][2][rr] + acc[mq][3][rr];
          float s2 = acc[mq][0][rr]*acc[mq][0][rr] + acc[mq][1][rr]*acc[mq][1][rr]
                   + acc[mq][2][rr]*acc[mq][2][rr] + acc[mq][3][rr]*acc[mq][3][rr];
#pragma unroll
          for (int off = 1; off < 16; off <<= 1) {
            s  += __shfl_xor(s,  off, 64);
            s2 += __shfl_xor(s2, off, 64);
          }
          float mu   = s * (1.0f / 64.0f);
          float var  = fmaxf(s2 * (1.0f / 64.0f) - mu * mu, 0.f);
          float rstd = rsqrtf(var + EPS);
#pragma unroll
          for (int nq = 0; nq < 4; nq++)
            acc[mq][nq][rr] = (acc[mq][nq][rr] - mu) * rstd * gv[nq] + bev[nq];
        }
    }

    unsigned short* dst = isQ ? Qws : Kws;
    const int head = isQ ? g : g - 16;
#pragma unroll
    for (int mq = 0; mq < 4; mq++)
#pragma unroll
      for (int rr = 0; rr < 4; rr++) {
        int m = m0 + mh * 64 + mq * 16 + quad * 4 + rr;
        int b = m >> 11, s = m & 2047;
        long base = ((long)((b * 16 + head) * 2048 + s)) * 64;
#pragma unroll
        for (int nq = 0; nq < 4; nq++)
          dst[base + nq * 16 + l15] = f2bf(acc[mq][nq][rr]);
      }
  } else {
    // ---------------- V^T GEMM 128x64: Vt[bh][d][s] ----------------
    const int id2 = id - 512;
    const int n0 = (id2 & 31) * 64, m0 = ((id2 >> 5) & 7) * 128, bz = id2 >> 8;
    const long xrow0 = (long)bz * 2048;
    const unsigned short* WvT = WT + 2048L * 1024;

    f32x4 acc[4][2];
#pragma unroll
    for (int i = 0; i < 4; i++)
#pragma unroll
      for (int j = 0; j < 2; j++) acc[i][j] = (f32x4){0.f, 0.f, 0.f, 0.f};

    if (use_xbf) {
      const long gva = (long)(m0 + w * 32 + grow) * 1024 + gcol;
      const long gvb = (xrow0 + n0 + w * 16 + grow) * 1024 + gcol;
#define STAGE_V(bf, kk) do { \
        glds16(&WvT[gva + (kk)],             &As[bf][(w * 32) * 32]); \
        glds16(&WvT[gva + (kk) + 16 * 1024], &As[bf][(w * 32 + 16) * 32]); \
        glds16(&Xbf[gvb + (kk)],             &Bs[bf][(w * 16) * 32]); \
      } while (0)
      STAGE_V(0, 0);
      __syncthreads();
      int buf = 0;
      for (int kt = 0; kt < 1024; kt += 32) {
        if (kt + 32 < 1024) STAGE_V(buf ^ 1, kt + 32);
        bf16x8 af[4], bfr[2];
#pragma unroll
        for (int mq = 0; mq < 4; mq++)
          af[mq] = *(const bf16x8*)&As[buf][(mh * 64 + mq * 16 + l15) * 32 + quad * 8];
#pragma unroll
        for (int nq = 0; nq < 2; nq++)
          bfr[nq] = *(const bf16x8*)&Bs[buf][(nh * 32 + nq * 16 + l15) * 32 + quad * 8];
#pragma unroll
        for (int mq = 0; mq < 4; mq++)
#pragma unroll
          for (int nq = 0; nq < 2; nq++)
            acc[mq][nq] = __builtin_amdgcn_mfma_f32_16x16x32_bf16(af[mq], bfr[nq], acc[mq][nq], 0, 0, 0);
        __syncthreads();
        buf ^= 1;
      }
#undef STAGE_V
    } else {
      const int srA = tid >> 1, shA = (tid & 1) * 16;
      const int srB = tid >> 2, shB = (tid & 3) * 8;
      {
        long wo = (long)(m0 + srA) * 1024 + shA;
        *(uint4*)&As[0][srA * 32 + shA]     = *(const uint4*)&WvT[wo];
        *(uint4*)&As[0][srA * 32 + shA + 8] = *(const uint4*)&WvT[wo + 8];
        long xo = (xrow0 + n0 + srB) * 1024 + shB;
        float4 a0 = *(const float4*)&Xf[xo];
        float4 a1 = *(const float4*)&Xf[xo + 4];
        unsigned short v[8] = {f2bf(a0.x), f2bf(a0.y), f2bf(a0.z), f2bf(a0.w),
                               f2bf(a1.x), f2bf(a1.y), f2bf(a1.z), f2bf(a1.w)};
        *(uint4*)&Bs[0][srB * 32 + shB] = *(uint4*)v;
      }
      __syncthreads();

      int buf = 0;
      for (int kt = 0; kt < 1024; kt += 32) {
        const int nbuf = buf ^ 1;
        const bool pf = (kt + 32) < 1024;
        uint4 wv0, wv1;
        float4 a0, a1;
        if (pf) {
          long wo = (long)(m0 + srA) * 1024 + kt + 32 + shA;
          wv0 = *(const uint4*)&WvT[wo];
          wv1 = *(const uint4*)&WvT[wo + 8];
          long xo = (xrow0 + n0 + srB) * 1024 + kt + 32 + shB;
          a0 = *(const float4*)&Xf[xo];
          a1 = *(const float4*)&Xf[xo + 4];
        }

        bf16x8 af[4], bfr[2];
#pragma unroll
        for (int mq = 0; mq < 4; mq++)
          af[mq] = *(const bf16x8*)&As[buf][(mh * 64 + mq * 16 + l15) * 32 + quad * 8];
#pragma unroll
        for (int nq = 0; nq < 2; nq++)
          bfr[nq] = *(const bf16x8*)&Bs[buf][(nh * 32 + nq * 16 + l15) * 32 + quad * 8];
#pragma unroll
        for (int mq = 0; mq < 4; mq++)
#pragma unroll
          for (int nq = 0; nq < 2; nq++)
            acc[mq][nq] = __builtin_amdgcn_mfma_f32_16x16x32_bf16(af[mq], bfr[nq], acc[mq][nq], 0, 0, 0);

        if (pf) {
          *(uint4*)&As[nbuf][srA * 32 + shA]     = wv0;
          *(uint4*)&As[nbuf][srA * 32 + shA + 8] = wv1;
          unsigned short v[8] = {f2bf(a0.x), f2bf(a0.y), f2bf(a0.z), f2bf(a0.w),
                                 f2bf(a1.x), f2bf(a1.y), f2bf(a1.z), f2bf(a1.w)};
          *(uint4*)&Bs[nbuf][srB * 32 + shB] = *(uint4*)v;
        }
        __syncthreads();
        buf = nbuf;
      }
    }

    const long outb = (long)bz * 2097152;
#pragma unroll
    for (int mq = 0; mq < 4; mq++)
#pragma unroll
      for (int rr = 0; rr < 4; rr++) {
        int m = m0 + mh * 64 + mq * 16 + quad * 4 + rr;
        float bv = bias[2048 + m];
#pragma unroll
        for (int nq = 0; nq < 2; nq++) {
          int n = n0 + nh * 32 + nq * 16 + l15;
          Vt[outb + (long)m * 2048 + n] = f2bf(acc[mq][nq][rr] + bv);
        }
      }
  }
}

// ---------------- Kernel 2: causal attention, 128-row q-tiles -------------
// 512 blocks x 512 threads; one 128-row q-tile per block, 8 waves x 16 rows.
// All waves share ONE double-buffered K/V stream (group 0 stages K, group 1
// stages V). Per-wave causal skip: wave w's 16 rows all lie in 64-block
// 2t+(w>>2), so active iff j <= 2t+(w>>2), mask iff equal. Block span
// 2t+2 steps; pairing t with 15-t makes co-resident span sums 34 (vs 49).
__global__ __launch_bounds__(512) void attn_kernel(
    unsigned short* __restrict__ Qws,        // in: Q (pre-scaled), out: O
    const unsigned short* __restrict__ Kws,
    const unsigned short* __restrict__ Vt)
{
  __shared__ __align__(16) unsigned short Ks[2][64 * 72];
  __shared__ __align__(16) unsigned short VTs[2][64 * 72];  // [d][s-kb]
  __shared__ __align__(16) unsigned short Ps[128 * 64];     // Q staging + P

  const int tid = threadIdx.x;
  const int w = tid >> 6, lane = tid & 63, quad = lane >> 4, l15 = lane & 15;
  const int g = w >> 2;                      // staging role: 0=K, 1=V
  const int id = blockIdx.x;
  const int bh = (id & 7) * 4 + ((id >> 3) & 3);
  const int i5 = id >> 5;                    // 0..15
  const int t  = (i5 < 8) ? i5 : 23 - i5;    // pair-balanced remap {t,15-t}
  const long bhoff = (long)bh * 2048 * 64;
  const long bhv   = (long)bh * 131072;      // 64*2048

  const int qbase  = t * 128;
  const int jsteps = 2 * t + 2;
  const int dj     = 2 * t + g;              // wave's diagonal step

  // Q/P staging: 512 threads cover 128 rows x 64 cols
  const int qr = tid >> 2, qc = (tid & 3) * 16;
  const int qsw = ((qr >> 2) & 3) << 4;
  // K/V staging: 256 threads per role
  const int t2 = tid & 255;
  const int sr = t2 >> 2, sc = (t2 & 3) * 16;
  const int sw = ((l15 >> 2) & 3) << 4;
  const int pc0 = (quad * 8) ^ sw;
  const int pc1 = (32 + quad * 8) ^ sw;

  bf16x8 ones;
  {
    union { unsigned short u[8]; bf16x8 v; } c;
#pragma unroll
    for (int i = 0; i < 8; i++) c.u[i] = 0x3F80u;
    ones = c.v;
  }

  // Q: all 512 threads load the 128-row tile into Ps (swizzled)
  *(uint4*)&Ps[qr * 64 + (qc ^ qsw)]       = *(const uint4*)&Qws[bhoff + (qbase + qr) * 64 + qc];
  *(uint4*)&Ps[qr * 64 + ((qc ^ qsw) + 8)] = *(const uint4*)&Qws[bhoff + (qbase + qr) * 64 + qc + 8];
  // K by group 0, V by group 1
  if (g == 0) {
    *(uint4*)&Ks[0][sr * 72 + sc]      = *(const uint4*)&Kws[bhoff + sr * 64 + sc];
    *(uint4*)&Ks[0][sr * 72 + sc + 8]  = *(const uint4*)&Kws[bhoff + sr * 64 + sc + 8];
  } else {
    *(uint4*)&VTs[0][sr * 72 + sc]     = *(const uint4*)&Vt[bhv + sr * 2048 + sc];
    *(uint4*)&VTs[0][sr * 72 + sc + 8] = *(const uint4*)&Vt[bhv + sr * 2048 + sc + 8];
  }
  __syncthreads();

  const bf16x8 qf0 = *(const bf16x8*)&Ps[(w * 16 + l15) * 64 + pc0];
  const bf16x8 qf1 = *(const bf16x8*)&Ps[(w * 16 + l15) * 64 + pc1];

  f32x4 o[4], osum;
#pragma unroll
  for (int i = 0; i < 4; i++) o[i] = (f32x4){0.f, 0.f, 0.f, 0.f};
  osum = (f32x4){0.f, 0.f, 0.f, 0.f};

  int cb = 0;
  for (int j = 0; j < jsteps; j++) {
    const int kb = j * 64;
    const bool pf = (j + 1) < jsteps;
    uint4 p0, p1;
    if (pf) {
      const int kb1 = kb + 64;
      if (g == 0) {
        p0 = *(const uint4*)&Kws[bhoff + (kb1 + sr) * 64 + sc];
        p1 = *(const uint4*)&Kws[bhoff + (kb1 + sr) * 64 + sc + 8];
      } else {
        p0 = *(const uint4*)&Vt[bhv + sr * 2048 + kb1 + sc];
        p1 = *(const uint4*)&Vt[bhv + sr * 2048 + kb1 + sc + 8];
      }
    }

    if (j <= dj) {                          // per-wave causal skip
      f32x4 sacc[4];
#pragma unroll
      for (int i = 0; i < 4; i++) sacc[i] = (f32x4){0.f, 0.f, 0.f, 0.f};
#pragma unroll
      for (int nt = 0; nt < 4; nt++) {
        bf16x8 kf0 = *(const bf16x8*)&Ks[cb][(nt * 16 + l15) * 72 + quad * 8];
        bf16x8 kf1 = *(const bf16x8*)&Ks[cb][(nt * 16 + l15) * 72 + 32 + quad * 8];
        sacc[nt] = __builtin_amdgcn_mfma_f32_16x16x32_bf16(qf0, kf0, sacc[nt], 0, 0, 0);
        sacc[nt] = __builtin_amdgcn_mfma_f32_16x16x32_bf16(qf1, kf1, sacc[nt], 0, 0, 0);
      }

      const bool domask = (j == dj);
#pragma unroll
      for (int nt = 0; nt < 4; nt++)
#pragma unroll
        for (int rr = 0; rr < 4; rr++) {
          float p = exp2f(sacc[nt][rr]);
          if (domask) {
            int kcol = kb + nt * 16 + l15;
            int qrow = qbase + w * 16 + quad * 4 + rr;
            if (kcol > qrow) p = 0.f;
          }
          sacc[nt][rr] = p;
        }

#pragma unroll
      for (int rr = 0; rr < 4; rr++)
#pragma unroll
        for (int nt = 0; nt < 4; nt++)
          Ps[(w * 16 + quad * 4 + rr) * 64 + (((nt ^ quad) & 3) * 16 + l15)]
              = f2bf_t(sacc[nt][rr]);

      bf16x8 pfr0 = *(const bf16x8*)&Ps[(w * 16 + l15) * 64 + pc0];
      bf16x8 pfr1 = *(const bf16x8*)&Ps[(w * 16 + l15) * 64 + pc1];

      osum = __builtin_amdgcn_mfma_f32_16x16x32_bf16(pfr0, ones, osum, 0, 0, 0);
      osum = __builtin_amdgcn_mfma_f32_16x16x32_bf16(pfr1, ones, osum, 0, 0, 0);
#pragma unroll
      for (int dt = 0; dt < 4; dt++) {
        bf16x8 vf0 = *(const bf16x8*)&VTs[cb][(dt * 16 + l15) * 72 + quad * 8];
        bf16x8 vf1 = *(const bf16x8*)&VTs[cb][(dt * 16 + l15) * 72 + 32 + quad * 8];
        o[dt] = __builtin_amdgcn_mfma_f32_16x16x32_bf16(pfr0, vf0, o[dt], 0, 0, 0);
        o[dt] = __builtin_amdgcn_mfma_f32_16x16x32_bf16(pfr1, vf1, o[dt], 0, 0, 0);
      }
    }

    if (pf) {
      const int nb = cb ^ 1;
      if (g == 0) {
        *(uint4*)&Ks[nb][sr * 72 + sc]      = p0;
        *(uint4*)&Ks[nb][sr * 72 + sc + 8]  = p1;
      } else {
        *(uint4*)&VTs[nb][sr * 72 + sc]     = p0;
        *(uint4*)&VTs[nb][sr * 72 + sc + 8] = p1;
      }
      __syncthreads();
      cb = nb;
    }
  }

#pragma unroll
  for (int rr = 0; rr < 4; rr++) {
    float inv = 1.0f / osum[rr];
    int row = qbase + w * 16 + quad * 4 + rr;
    long base = bhoff + (long)row * 64;
#pragma unroll
    for (int dt = 0; dt < 4; dt++)
      Qws[base + dt * 16 + l15] = f2bf(o[dt][rr] * inv);
  }
}

// ---------------- Kernel 3: output projection, 128x64 tiles (r0 proven) ---
__global__ __launch_bounds__(256) void proj_kernel(
    const unsigned short* __restrict__ AQ,
    const unsigned short* __restrict__ WT,
    const float* __restrict__ bias,
    float* __restrict__ Out)
{
  __shared__ __align__(16) unsigned short As[2][128 * 32];
  __shared__ __align__(16) unsigned short Bs[2][64 * 32];

  const int tid = threadIdx.x;
  const int w = tid >> 6, lane = tid & 63, quad = lane >> 4, l15 = lane & 15;
  const int mh = w & 1, nh = w >> 1;
  const int n0 = blockIdx.x * 64, m0 = blockIdx.y * 128;

  f32x4 acc[4][2];
#pragma unroll
  for (int i = 0; i < 4; i++)
#pragma unroll
    for (int j = 0; j < 2; j++) acc[i][j] = (f32x4){0.f, 0.f, 0.f, 0.f};

  const int srA = tid >> 1, shA = (tid & 1) * 16;
  const int srB = tid >> 2, shB = (tid & 3) * 8;
  const int m = m0 + srA, b = m >> 11, s = m & 2047;

  {
    const int h = shA >> 6, d = shA & 63;
    long ao = ((long)((b * 16 + h) * 2048 + s)) * 64 + d;
    *(uint4*)&As[0][srA * 32 + shA]     = *(const uint4*)&AQ[ao];
    *(uint4*)&As[0][srA * 32 + shA + 8] = *(const uint4*)&AQ[ao + 8];
    long wo = (long)(n0 + srB) * 1024 + shB;
    *(uint4*)&Bs[0][srB * 32 + shB] = *(const uint4*)&WT[wo];
  }
  __syncthreads();

  int buf = 0;
  for (int kt = 0; kt < 1024; kt += 32) {
    const int nbuf = buf ^ 1;
    const bool pf = (kt + 32) < 1024;
    uint4 av0, av1, wv0;
    if (pf) {
      const int k = kt + 32 + shA, h = k >> 6, d = k & 63;
      long ao = ((long)((b * 16 + h) * 2048 + s)) * 64 + d;
      av0 = *(const uint4*)&AQ[ao];
      av1 = *(const uint4*)&AQ[ao + 8];
      long wo = (long)(n0 + srB) * 1024 + kt + 32 + shB;
      wv0 = *(const uint4*)&WT[wo];
    }

    bf16x8 af[4], bfr[2];
#pragma unroll
    for (int mq = 0; mq < 4; mq++)
      af[mq] = *(const bf16x8*)&As[buf][(mh * 64 + mq * 16 + l15) * 32 + quad * 8];
#pragma unroll
    for (int nq = 0; nq < 2; nq++)
      bfr[nq] = *(const bf16x8*)&Bs[buf][(nh * 32 + nq * 16 + l15) * 32 + quad * 8];
#pragma unroll
    for (int mq = 0; mq < 4; mq++)
#pragma unroll
      for (int nq = 0; nq < 2; nq++)
        acc[mq][nq] = __builtin_amdgcn_mfma_f32_16x16x32_bf16(af[mq], bfr[nq], acc[mq][nq], 0, 0, 0);

    if (pf) {
      *(uint4*)&As[nbuf][srA * 32 + shA]     = av0;
      *(uint4*)&As[nbuf][srA * 32 + shA + 8] = av1;
      *(uint4*)&Bs[nbuf][srB * 32 + shB]     = wv0;
    }
    __syncthreads();
    buf = nbuf;
  }

#pragma unroll
  for (int nq = 0; nq < 2; nq++) {
    int n = n0 + nh * 32 + nq * 16 + l15;
    float bv = bias[n];
#pragma unroll
    for (int mq = 0; mq < 4; mq++)
#pragma unroll
      for (int rr = 0; rr < 4; rr++) {
        int mm = m0 + mh * 64 + mq * 16 + quad * 4 + rr;
        Out[(long)mm * 1024 + n] = acc[mq][nq][rr] + bv;
      }
  }
}

extern "C" void kernel_launch(void* const* d_in, const int* in_sizes, int n_in,
                              void* d_out, int out_size, void* d_ws, size_t ws_size,
                              hipStream_t stream) {
  const float* X  = (const float*)d_in[0];
  const float* Wa = (const float*)d_in[1];
  const float* ba = (const float*)d_in[2];
  const float* Wp = (const float*)d_in[3];
  const float* bp = (const float*)d_in[4];
  const float* qg = (const float*)d_in[5];
  const float* qb = (const float*)d_in[6];
  const float* kg = (const float*)d_in[7];
  const float* kb = (const float*)d_in[8];

  const long per = 2L * 16 * 2048 * 64;     // 4,194,304 shorts
  unsigned short* ws  = (unsigned short*)d_ws;
  unsigned short* Qws = ws;
  unsigned short* Kws = Qws + per;
  unsigned short* Vt  = Kws + per;          // [bh][64 d][2048 s]

  const bool big = ws_size >= (size_t)(5L * per * 2);
  unsigned short *Xbf, *WaT, *WpT;
  if (big) {
    Xbf = Vt + per;
    WaT = Xbf + per;
    WpT = WaT + 3072L * 1024;
  } else {
    Xbf = Qws;  // unused
    WaT = Vt + per;
    WpT = WaT + 3072L * 1024;
  }

  prep_kernel<<<big ? 2048 : 1024, 256, 0, stream>>>(Wa, Wp, X, WaT, WpT, Xbf);
  qkvt_kernel<<<1024, 256, 0, stream>>>(X, Xbf, big ? 1 : 0, WaT, ba,
                                        qg, qb, kg, kb, Qws, Kws, Vt);
  attn_kernel<<<512, 512, 0, stream>>>(Qws, Kws, Vt);
  proj_kernel<<<dim3(16, 32), 256, 0, stream>>>(Qws, WpT, bp, (float*)d_out);
}

// Round 13
// 204.230 us; speedup vs baseline: 1.0288x; 1.0288x over previous
//
#include <hip/hip_runtime.h>
#include <hip/hip_bf16.h>

typedef __bf16 bf16x8 __attribute__((ext_vector_type(8)));
typedef float f32x4 __attribute__((ext_vector_type(4)));

#define EPS 1e-5f
// 0.125 * log2(e): folded into Q via LN gamma/beta in qkv, so P = exp2(S)
#define QSCALE 0.18033688011112042f

__device__ __forceinline__ unsigned short f2bf(float f) {
  union { float f; unsigned int i; } c; c.f = f;
  unsigned int r = c.i + 0x7FFFu + ((c.i >> 16) & 1u);
  return (unsigned short)(r >> 16);
}
// truncating fp32->bf16 (for P>=0: <=1ulp, saves the rounding chain)
__device__ __forceinline__ unsigned short f2bf_t(float f) {
  union { float f; unsigned int i; } c; c.f = f;
  return (unsigned short)(c.i >> 16);
}

// async global->LDS DMA, 16B per lane. LDS dest must be wave-uniform base
// (HW writes base + lane*16); global src is per-lane.
__device__ __forceinline__ void glds16(const void* g, void* l) {
  __builtin_amdgcn_global_load_lds(
      (const __attribute__((address_space(1))) unsigned int*)g,
      (__attribute__((address_space(3))) unsigned int*)l, 16, 0, 0);
}

// ---------------- Prep: both weight transposes + optional X convert -------
__device__ __forceinline__ void transpose_tile(
    const float* __restrict__ in, unsigned short* __restrict__ out,
    int R, int C, int ct0, int rt0, unsigned short* S /*64*72*/)
{
  const int t = threadIdx.x;
  const int r = t >> 2, c4 = (t & 3) * 16;
  {
    long base = (long)(rt0 + r) * C + ct0 + c4;
    float4 a = *(const float4*)&in[base];
    float4 b = *(const float4*)&in[base + 4];
    float4 c = *(const float4*)&in[base + 8];
    float4 d = *(const float4*)&in[base + 12];
    unsigned short v[16] = {f2bf(a.x), f2bf(a.y), f2bf(a.z), f2bf(a.w),
                            f2bf(b.x), f2bf(b.y), f2bf(b.z), f2bf(b.w),
                            f2bf(c.x), f2bf(c.y), f2bf(c.z), f2bf(c.w),
                            f2bf(d.x), f2bf(d.y), f2bf(d.z), f2bf(d.w)};
    *(uint4*)&S[r * 72 + c4]     = *(uint4*)&v[0];
    *(uint4*)&S[r * 72 + c4 + 8] = *(uint4*)&v[8];
  }
  __syncthreads();
  unsigned short tmp[16];
#pragma unroll
  for (int j = 0; j < 16; j++) tmp[j] = S[(c4 + j) * 72 + r];
  *(uint4*)&out[(long)(ct0 + r) * R + rt0 + c4]     = *(uint4*)&tmp[0];
  *(uint4*)&out[(long)(ct0 + r) * R + rt0 + c4 + 8] = *(uint4*)&tmp[8];
}

__global__ __launch_bounds__(256) void prep_kernel(
    const float* __restrict__ Wa, const float* __restrict__ Wp,
    const float* __restrict__ X,
    unsigned short* __restrict__ WaT, unsigned short* __restrict__ WpT,
    unsigned short* __restrict__ Xbf)
{
  __shared__ __align__(16) unsigned short S[64 * 72];
  const int id = blockIdx.x;
  if (id < 768) {                    // Wa [1024,3072] -> WaT [3072,1024]
    transpose_tile(Wa, WaT, 1024, 3072, (id % 48) * 64, (id / 48) * 64, S);
  } else if (id < 1024) {            // Wp [1024,1024] -> WpT [1024,1024]
    const int i2 = id - 768;
    transpose_tile(Wp, WpT, 1024, 1024, (i2 % 16) * 64, (i2 / 16) * 64, S);
  } else {                           // X fp32 -> bf16 (big-ws only)
    long i = ((long)(id - 1024) * 256 + threadIdx.x) * 16;
    float4 a = *(const float4*)&X[i];
    float4 b = *(const float4*)&X[i + 4];
    float4 c = *(const float4*)&X[i + 8];
    float4 d = *(const float4*)&X[i + 12];
    unsigned short v[16] = {f2bf(a.x), f2bf(a.y), f2bf(a.z), f2bf(a.w),
                            f2bf(b.x), f2bf(b.y), f2bf(b.z), f2bf(b.w),
                            f2bf(c.x), f2bf(c.y), f2bf(c.z), f2bf(c.w),
                            f2bf(d.x), f2bf(d.y), f2bf(d.z), f2bf(d.w)};
    *(uint4*)&Xbf[i]     = *(uint4*)&v[0];
    *(uint4*)&Xbf[i + 8] = *(uint4*)&v[8];
  }
}

// ---------- Merged GEMM: blocks 0..511 Q/K+LN, 512..1023 V^T --------------
// bf16 path: glds16 into 2-buffer LDS (r1-proven best: 58us, 4 blk/CU).
__global__ __launch_bounds__(256) void qkvt_kernel(
    const float* __restrict__ Xf,
    const unsigned short* __restrict__ Xbf, int use_xbf,
    const unsigned short* __restrict__ WT,    // WaT [3072,1024]
    const float* __restrict__ bias,           // b_attn [3072]
    const float* __restrict__ qg, const float* __restrict__ qb,
    const float* __restrict__ kg, const float* __restrict__ kb,
    unsigned short* __restrict__ Qws, unsigned short* __restrict__ Kws,
    unsigned short* __restrict__ Vt)
{
  __shared__ __align__(16) unsigned short As[2][128 * 32];
  __shared__ __align__(16) unsigned short Bs[2][128 * 32];

  const int tid = threadIdx.x;
  const int w = tid >> 6, lane = tid & 63, quad = lane >> 4, l15 = lane & 15;
  const int mh = w & 1, nh = w >> 1;
  const int id = blockIdx.x;
  // glds addressing: each wave stages contiguous 16-row groups; lane covers
  // row (lane>>2) of the group, 16B column chunk (lane&3).
  const int grow = lane >> 2, gcol = (lane & 3) * 8;

  if (id < 512) {
    // ---------------- Q/K GEMM 128x128 + QK-LN ----------------
    const int n0 = (id & 15) * 128, m0 = (id >> 4) * 128;

    f32x4 acc[4][4];
#pragma unroll
    for (int i = 0; i < 4; i++)
#pragma unroll
      for (int j = 0; j < 4; j++) acc[i][j] = (f32x4){0.f, 0.f, 0.f, 0.f};

    if (use_xbf) {
      const long ga = (long)(m0 + w * 32 + grow) * 1024 + gcol;
      const long gb = (long)(n0 + w * 32 + grow) * 1024 + gcol;
#define STAGE_QK(bf, kk) do { \
        glds16(&Xbf[ga + (kk)],             &As[bf][(w * 32) * 32]); \
        glds16(&Xbf[ga + (kk) + 16 * 1024], &As[bf][(w * 32 + 16) * 32]); \
        glds16(&WT[gb + (kk)],              &Bs[bf][(w * 32) * 32]); \
        glds16(&WT[gb + (kk) + 16 * 1024],  &Bs[bf][(w * 32 + 16) * 32]); \
      } while (0)
      STAGE_QK(0, 0);
      __syncthreads();
      int buf = 0;
      for (int kt = 0; kt < 1024; kt += 32) {
        if (kt + 32 < 1024) STAGE_QK(buf ^ 1, kt + 32);
        bf16x8 af[4], bfr[4];
#pragma unroll
        for (int mq = 0; mq < 4; mq++)
          af[mq] = *(const bf16x8*)&As[buf][(mh * 64 + mq * 16 + l15) * 32 + quad * 8];
#pragma unroll
        for (int nq = 0; nq < 4; nq++)
          bfr[nq] = *(const bf16x8*)&Bs[buf][(nh * 64 + nq * 16 + l15) * 32 + quad * 8];
#pragma unroll
        for (int mq = 0; mq < 4; mq++)
#pragma unroll
          for (int nq = 0; nq < 4; nq++)
            acc[mq][nq] = __builtin_amdgcn_mfma_f32_16x16x32_bf16(af[mq], bfr[nq], acc[mq][nq], 0, 0, 0);
        __syncthreads();
        buf ^= 1;
      }
#undef STAGE_QK
    } else {
      // -------- fp32-X fallback: reg-staged double buffer ------
      const int sr2 = tid >> 1, sh2 = (tid & 1) * 16;
      {
        long xo = (long)(m0 + sr2) * 1024 + sh2;
        float4 a0 = *(const float4*)&Xf[xo];
        float4 a1 = *(const float4*)&Xf[xo + 4];
        float4 a2 = *(const float4*)&Xf[xo + 8];
        float4 a3 = *(const float4*)&Xf[xo + 12];
        unsigned short v[16] = {f2bf(a0.x), f2bf(a0.y), f2bf(a0.z), f2bf(a0.w),
                                f2bf(a1.x), f2bf(a1.y), f2bf(a1.z), f2bf(a1.w),
                                f2bf(a2.x), f2bf(a2.y), f2bf(a2.z), f2bf(a2.w),
                                f2bf(a3.x), f2bf(a3.y), f2bf(a3.z), f2bf(a3.w)};
        *(uint4*)&As[0][sr2 * 32 + sh2]     = *(uint4*)&v[0];
        *(uint4*)&As[0][sr2 * 32 + sh2 + 8] = *(uint4*)&v[8];
        long wo = (long)(n0 + sr2) * 1024 + sh2;
        *(uint4*)&Bs[0][sr2 * 32 + sh2]     = *(const uint4*)&WT[wo];
        *(uint4*)&Bs[0][sr2 * 32 + sh2 + 8] = *(const uint4*)&WT[wo + 8];
      }
      __syncthreads();

      int buf = 0;
      for (int kt = 0; kt < 1024; kt += 32) {
        const int nbuf = buf ^ 1;
        const bool pf = (kt + 32) < 1024;
        uint4 wv0, wv1;
        float4 a0, a1, a2, a3;
        if (pf) {
          long xo = (long)(m0 + sr2) * 1024 + kt + 32 + sh2;
          a0 = *(const float4*)&Xf[xo];
          a1 = *(const float4*)&Xf[xo + 4];
          a2 = *(const float4*)&Xf[xo + 8];
          a3 = *(const float4*)&Xf[xo + 12];
          long wo = (long)(n0 + sr2) * 1024 + kt + 32 + sh2;
          wv0 = *(const uint4*)&WT[wo];
          wv1 = *(const uint4*)&WT[wo + 8];
        }

        bf16x8 af[4], bfr[4];
#pragma unroll
        for (int mq = 0; mq < 4; mq++)
          af[mq] = *(const bf16x8*)&As[buf][(mh * 64 + mq * 16 + l15) * 32 + quad * 8];
#pragma unroll
        for (int nq = 0; nq < 4; nq++)
          bfr[nq] = *(const bf16x8*)&Bs[buf][(nh * 64 + nq * 16 + l15) * 32 + quad * 8];
#pragma unroll
        for (int mq = 0; mq < 4; mq++)
#pragma unroll
          for (int nq = 0; nq < 4; nq++)
            acc[mq][nq] = __builtin_amdgcn_mfma_f32_16x16x32_bf16(af[mq], bfr[nq], acc[mq][nq], 0, 0, 0);

        if (pf) {
          unsigned short v[16] = {f2bf(a0.x), f2bf(a0.y), f2bf(a0.z), f2bf(a0.w),
                                  f2bf(a1.x), f2bf(a1.y), f2bf(a1.z), f2bf(a1.w),
                                  f2bf(a2.x), f2bf(a2.y), f2bf(a2.z), f2bf(a2.w),
                                  f2bf(a3.x), f2bf(a3.y), f2bf(a3.z), f2bf(a3.w)};
          *(uint4*)&As[nbuf][sr2 * 32 + sh2]     = *(uint4*)&v[0];
          *(uint4*)&As[nbuf][sr2 * 32 + sh2 + 8] = *(uint4*)&v[8];
          *(uint4*)&Bs[nbuf][sr2 * 32 + sh2]     = wv0;
          *(uint4*)&Bs[nbuf][sr2 * 32 + sh2 + 8] = wv1;
        }
        __syncthreads();
        buf = nbuf;
      }
    }

#pragma unroll
    for (int nq = 0; nq < 4; nq++) {
      float bv = bias[n0 + nh * 64 + nq * 16 + l15];
#pragma unroll
      for (int mq = 0; mq < 4; mq++)
#pragma unroll
        for (int rr = 0; rr < 4; rr++) acc[mq][nq][rr] += bv;
    }

    const int g = (n0 >> 6) + nh;   // 0..31: Q heads then K heads
    const bool isQ = g < 16;
    {
      float gv[4], bev[4];
#pragma unroll
      for (int nq = 0; nq < 4; nq++) {
        int d = nq * 16 + l15;
        gv[nq]  = isQ ? qg[d] : kg[d];
        bev[nq] = isQ ? qb[d] : kb[d];
        if (isQ) { gv[nq] *= QSCALE; bev[nq] *= QSCALE; }
      }
#pragma unroll
      for (int mq = 0; mq < 4; mq++)
#pragma unroll
        for (int rr = 0; rr < 4; rr++) {
          float s  = acc[mq][0][rr] + acc[mq][1][rr] + acc[mq][2][rr] + acc[mq][3][rr];
          float s2 = acc[mq][0][rr]*acc[mq][0][rr] + acc[mq][1][rr]*acc[mq][1][rr]
                   + acc[mq][2][rr]*acc[mq][2][rr] + acc[mq][3][rr]*acc[mq][3][rr];
#pragma unroll
          for (int off = 1; off < 16; off <<= 1) {
            s  += __shfl_xor(s,  off, 64);
            s2 += __shfl_xor(s2, off, 64);
          }
          float mu   = s * (1.0f / 64.0f);
          float var  = fmaxf(s2 * (1.0f / 64.0f) - mu * mu, 0.f);
          float rstd = rsqrtf(var + EPS);
#pragma unroll
          for (int nq = 0; nq < 4; nq++)
            acc[mq][nq][rr] = (acc[mq][nq][rr] - mu) * rstd * gv[nq] + bev[nq];
        }
    }

    unsigned short* dst = isQ ? Qws : Kws;
    const int head = isQ ? g : g - 16;
#pragma unroll
    for (int mq = 0; mq < 4; mq++)
#pragma unroll
      for (int rr = 0; rr < 4; rr++) {
        int m = m0 + mh * 64 + mq * 16 + quad * 4 + rr;
        int b = m >> 11, s = m & 2047;
        long base = ((long)((b * 16 + head) * 2048 + s)) * 64;
#pragma unroll
        for (int nq = 0; nq < 4; nq++)
          dst[base + nq * 16 + l15] = f2bf(acc[mq][nq][rr]);
      }
  } else {
    // ---------------- V^T GEMM 128x64: Vt[bh][d][s] ----------------
    const int id2 = id - 512;
    const int n0 = (id2 & 31) * 64, m0 = ((id2 >> 5) & 7) * 128, bz = id2 >> 8;
    const long xrow0 = (long)bz * 2048;
    const unsigned short* WvT = WT + 2048L * 1024;

    f32x4 acc[4][2];
#pragma unroll
    for (int i = 0; i < 4; i++)
#pragma unroll
      for (int j = 0; j < 2; j++) acc[i][j] = (f32x4){0.f, 0.f, 0.f, 0.f};

    if (use_xbf) {
      const long gva = (long)(m0 + w * 32 + grow) * 1024 + gcol;
      const long gvb = (xrow0 + n0 + w * 16 + grow) * 1024 + gcol;
#define STAGE_V(bf, kk) do { \
        glds16(&WvT[gva + (kk)],             &As[bf][(w * 32) * 32]); \
        glds16(&WvT[gva + (kk) + 16 * 1024], &As[bf][(w * 32 + 16) * 32]); \
        glds16(&Xbf[gvb + (kk)],             &Bs[bf][(w * 16) * 32]); \
      } while (0)
      STAGE_V(0, 0);
      __syncthreads();
      int buf = 0;
      for (int kt = 0; kt < 1024; kt += 32) {
        if (kt + 32 < 1024) STAGE_V(buf ^ 1, kt + 32);
        bf16x8 af[4], bfr[2];
#pragma unroll
        for (int mq = 0; mq < 4; mq++)
          af[mq] = *(const bf16x8*)&As[buf][(mh * 64 + mq * 16 + l15) * 32 + quad * 8];
#pragma unroll
        for (int nq = 0; nq < 2; nq++)
          bfr[nq] = *(const bf16x8*)&Bs[buf][(nh * 32 + nq * 16 + l15) * 32 + quad * 8];
#pragma unroll
        for (int mq = 0; mq < 4; mq++)
#pragma unroll
          for (int nq = 0; nq < 2; nq++)
            acc[mq][nq] = __builtin_amdgcn_mfma_f32_16x16x32_bf16(af[mq], bfr[nq], acc[mq][nq], 0, 0, 0);
        __syncthreads();
        buf ^= 1;
      }
#undef STAGE_V
    } else {
      const int srA = tid >> 1, shA = (tid & 1) * 16;
      const int srB = tid >> 2, shB = (tid & 3) * 8;
      {
        long wo = (long)(m0 + srA) * 1024 + shA;
        *(uint4*)&As[0][srA * 32 + shA]     = *(const uint4*)&WvT[wo];
        *(uint4*)&As[0][srA * 32 + shA + 8] = *(const uint4*)&WvT[wo + 8];
        long xo = (xrow0 + n0 + srB) * 1024 + shB;
        float4 a0 = *(const float4*)&Xf[xo];
        float4 a1 = *(const float4*)&Xf[xo + 4];
        unsigned short v[8] = {f2bf(a0.x), f2bf(a0.y), f2bf(a0.z), f2bf(a0.w),
                               f2bf(a1.x), f2bf(a1.y), f2bf(a1.z), f2bf(a1.w)};
        *(uint4*)&Bs[0][srB * 32 + shB] = *(uint4*)v;
      }
      __syncthreads();

      int buf = 0;
      for (int kt = 0; kt < 1024; kt += 32) {
        const int nbuf = buf ^ 1;
        const bool pf = (kt + 32) < 1024;
        uint4 wv0, wv1, xv0;
        float4 a0, a1;
        if (pf) {
          long wo = (long)(m0 + srA) * 1024 + kt + 32 + shA;
          wv0 = *(const uint4*)&WvT[wo];
          wv1 = *(const uint4*)&WvT[wo + 8];
          long xo = (xrow0 + n0 + srB) * 1024 + kt + 32 + shB;
          a0 = *(const float4*)&Xf[xo];
          a1 = *(const float4*)&Xf[xo + 4];
        }

        bf16x8 af[4], bfr[2];
#pragma unroll
        for (int mq = 0; mq < 4; mq++)
          af[mq] = *(const bf16x8*)&As[buf][(mh * 64 + mq * 16 + l15) * 32 + quad * 8];
#pragma unroll
        for (int nq = 0; nq < 2; nq++)
          bfr[nq] = *(const bf16x8*)&Bs[buf][(nh * 32 + nq * 16 + l15) * 32 + quad * 8];
#pragma unroll
        for (int mq = 0; mq < 4; mq++)
#pragma unroll
          for (int nq = 0; nq < 2; nq++)
            acc[mq][nq] = __builtin_amdgcn_mfma_f32_16x16x32_bf16(af[mq], bfr[nq], acc[mq][nq], 0, 0, 0);

        if (pf) {
          *(uint4*)&As[nbuf][srA * 32 + shA]     = wv0;
          *(uint4*)&As[nbuf][srA * 32 + shA + 8] = wv1;
          unsigned short v[8] = {f2bf(a0.x), f2bf(a0.y), f2bf(a0.z), f2bf(a0.w),
                                 f2bf(a1.x), f2bf(a1.y), f2bf(a1.z), f2bf(a1.w)};
          *(uint4*)&Bs[nbuf][srB * 32 + shB] = *(uint4*)v;
        }
        __syncthreads();
        buf = nbuf;
      }
    }

    const long outb = (long)bz * 2097152;
#pragma unroll
    for (int mq = 0; mq < 4; mq++)
#pragma unroll
      for (int rr = 0; rr < 4; rr++) {
        int m = m0 + mh * 64 + mq * 16 + quad * 4 + rr;
        float bv = bias[2048 + m];
#pragma unroll
        for (int nq = 0; nq < 2; nq++) {
          int n = n0 + nh * 32 + nq * 16 + l15;
          Vt[outb + (long)m * 2048 + n] = f2bf(acc[mq][nq][rr] + bv);
        }
      }
  }
}

// ---------------- Kernel 2: causal attention, paired q-tiles --------------
// 512 blocks x 512 threads. Waves 0-3 own tile (31-x), waves 4-7 own tile x;
// the short tile's K/V needs are a prefix of the long tile's, so both groups
// share ONE double-buffered K/V stream (group 0 stages K, group 1 stages V).
// Block span: 32-x steps vs 33 sequential. x remapped so co-resident blocks
// (id, id+256 -> same CU under XCD round-robin) have spans summing to 49.
__global__ __launch_bounds__(512) void attn_kernel(
    unsigned short* __restrict__ Qws,        // in: Q (pre-scaled), out: O
    const unsigned short* __restrict__ Kws,
    const unsigned short* __restrict__ Vt)
{
  __shared__ __align__(16) unsigned short Ks[2][64 * 72];
  __shared__ __align__(16) unsigned short VTs[2][64 * 72];  // [d][s-kb]
  __shared__ __align__(16) unsigned short Ps[2][64 * 64];   // per-group P/Q

  const int tid = threadIdx.x;
  const int w = tid >> 6, lane = tid & 63, quad = lane >> 4, l15 = lane & 15;
  const int g = w >> 2, wq = w & 3;          // group, wave-in-group
  const int id = blockIdx.x;
  const int bh = (id & 7) * 4 + ((id >> 3) & 3);
  const int i5 = id >> 5;                    // 0..15
  const int x  = (i5 < 8) ? i5 : 23 - i5;    // pair-balanced remap
  const long bhoff = (long)bh * 2048 * 64;
  const long bhv   = (long)bh * 131072;      // 64*2048

  const int qt_long = 31 - x;
  const int myqt  = g ? x : qt_long;
  const int qbase = myqt * 64;
  const int jsteps = qt_long + 1;            // 32 - x

  const int t2 = tid & 255;
  const int sr = t2 >> 2, sc = (t2 & 3) * 16;
  const int qsw = ((sr >> 2) & 3) << 4;
  const int sw = ((l15 >> 2) & 3) << 4;
  const int pc0 = (quad * 8) ^ sw;
  const int pc1 = (32 + quad * 8) ^ sw;

  bf16x8 ones;
  {
    union { unsigned short u[8]; bf16x8 v; } c;
#pragma unroll
    for (int i = 0; i < 8; i++) c.u[i] = 0x3F80u;
    ones = c.v;
  }

  // Q: each group's 256 threads load their own tile into Ps[g]
  *(uint4*)&Ps[g][sr * 64 + (sc ^ qsw)]       = *(const uint4*)&Qws[bhoff + (qbase + sr) * 64 + sc];
  *(uint4*)&Ps[g][sr * 64 + ((sc ^ qsw) + 8)] = *(const uint4*)&Qws[bhoff + (qbase + sr) * 64 + sc + 8];
  // K by group 0, V by group 1
  if (g == 0) {
    *(uint4*)&Ks[0][sr * 72 + sc]      = *(const uint4*)&Kws[bhoff + sr * 64 + sc];
    *(uint4*)&Ks[0][sr * 72 + sc + 8]  = *(const uint4*)&Kws[bhoff + sr * 64 + sc + 8];
  } else {
    *(uint4*)&VTs[0][sr * 72 + sc]     = *(const uint4*)&Vt[bhv + sr * 2048 + sc];
    *(uint4*)&VTs[0][sr * 72 + sc + 8] = *(const uint4*)&Vt[bhv + sr * 2048 + sc + 8];
  }
  __syncthreads();

  const bf16x8 qf0 = *(const bf16x8*)&Ps[g][(wq * 16 + l15) * 64 + pc0];
  const bf16x8 qf1 = *(const bf16x8*)&Ps[g][(wq * 16 + l15) * 64 + pc1];

  f32x4 o[4], osum;
#pragma unroll
  for (int i = 0; i < 4; i++) o[i] = (f32x4){0.f, 0.f, 0.f, 0.f};
  osum = (f32x4){0.f, 0.f, 0.f, 0.f};

  int cb = 0;
  for (int j = 0; j < jsteps; j++) {
    const int kb = j * 64;
    const bool pf = (j + 1) < jsteps;
    uint4 p0, p1;
    if (pf) {
      const int kb1 = kb + 64;
      if (g == 0) {
        p0 = *(const uint4*)&Kws[bhoff + (kb1 + sr) * 64 + sc];
        p1 = *(const uint4*)&Kws[bhoff + (kb1 + sr) * 64 + sc + 8];
      } else {
        p0 = *(const uint4*)&Vt[bhv + sr * 2048 + kb1 + sc];
        p1 = *(const uint4*)&Vt[bhv + sr * 2048 + kb1 + sc + 8];
      }
    }

    if (j <= myqt) {                        // short group idles past its tile
      f32x4 sacc[4];
#pragma unroll
      for (int i = 0; i < 4; i++) sacc[i] = (f32x4){0.f, 0.f, 0.f, 0.f};
#pragma unroll
      for (int nt = 0; nt < 4; nt++) {
        bf16x8 kf0 = *(const bf16x8*)&Ks[cb][(nt * 16 + l15) * 72 + quad * 8];
        bf16x8 kf1 = *(const bf16x8*)&Ks[cb][(nt * 16 + l15) * 72 + 32 + quad * 8];
        sacc[nt] = __builtin_amdgcn_mfma_f32_16x16x32_bf16(qf0, kf0, sacc[nt], 0, 0, 0);
        sacc[nt] = __builtin_amdgcn_mfma_f32_16x16x32_bf16(qf1, kf1, sacc[nt], 0, 0, 0);
      }

      const bool domask = (j == myqt);
#pragma unroll
      for (int nt = 0; nt < 4; nt++)
#pragma unroll
        for (int rr = 0; rr < 4; rr++) {
          float p = exp2f(sacc[nt][rr]);
          if (domask) {
            int kcol = kb + nt * 16 + l15;
            int qrow = qbase + wq * 16 + quad * 4 + rr;
            if (kcol > qrow) p = 0.f;
          }
          sacc[nt][rr] = p;
        }

#pragma unroll
      for (int rr = 0; rr < 4; rr++)
#pragma unroll
        for (int nt = 0; nt < 4; nt++)
          Ps[g][(wq * 16 + quad * 4 + rr) * 64 + (((nt ^ quad) & 3) * 16 + l15)]
              = f2bf_t(sacc[nt][rr]);

      bf16x8 pfr0 = *(const bf16x8*)&Ps[g][(wq * 16 + l15) * 64 + pc0];
      bf16x8 pfr1 = *(const bf16x8*)&Ps[g][(wq * 16 + l15) * 64 + pc1];

      osum = __builtin_amdgcn_mfma_f32_16x16x32_bf16(pfr0, ones, osum, 0, 0, 0);
      osum = __builtin_amdgcn_mfma_f32_16x16x32_bf16(pfr1, ones, osum, 0, 0, 0);
#pragma unroll
      for (int dt = 0; dt < 4; dt++) {
        bf16x8 vf0 = *(const bf16x8*)&VTs[cb][(dt * 16 + l15) * 72 + quad * 8];
        bf16x8 vf1 = *(const bf16x8*)&VTs[cb][(dt * 16 + l15) * 72 + 32 + quad * 8];
        o[dt] = __builtin_amdgcn_mfma_f32_16x16x32_bf16(pfr0, vf0, o[dt], 0, 0, 0);
        o[dt] = __builtin_amdgcn_mfma_f32_16x16x32_bf16(pfr1, vf1, o[dt], 0, 0, 0);
      }
    }

    if (pf) {
      const int nb = cb ^ 1;
      if (g == 0) {
        *(uint4*)&Ks[nb][sr * 72 + sc]      = p0;
        *(uint4*)&Ks[nb][sr * 72 + sc + 8]  = p1;
      } else {
        *(uint4*)&VTs[nb][sr * 72 + sc]     = p0;
        *(uint4*)&VTs[nb][sr * 72 + sc + 8] = p1;
      }
      __syncthreads();
      cb = nb;
    }
  }

#pragma unroll
  for (int rr = 0; rr < 4; rr++) {
    float inv = 1.0f / osum[rr];
    int row = qbase + wq * 16 + quad * 4 + rr;
    long base = bhoff + (long)row * 64;
#pragma unroll
    for (int dt = 0; dt < 4; dt++)
      Qws[base + dt * 16 + l15] = f2bf(o[dt][rr] * inv);
  }
}

// ---------------- Kernel 3: output projection, 128x64 tiles (r0 proven) ---
__global__ __launch_bounds__(256) void proj_kernel(
    const unsigned short* __restrict__ AQ,
    const unsigned short* __restrict__ WT,
    const float* __restrict__ bias,
    float* __restrict__ Out)
{
  __shared__ __align__(16) unsigned short As[2][128 * 32];
  __shared__ __align__(16) unsigned short Bs[2][64 * 32];

  const int tid = threadIdx.x;
  const int w = tid >> 6, lane = tid & 63, quad = lane >> 4, l15 = lane & 15;
  const int mh = w & 1, nh = w >> 1;
  const int n0 = blockIdx.x * 64, m0 = blockIdx.y * 128;

  f32x4 acc[4][2];
#pragma unroll
  for (int i = 0; i < 4; i++)
#pragma unroll
    for (int j = 0; j < 2; j++) acc[i][j] = (f32x4){0.f, 0.f, 0.f, 0.f};

  const int srA = tid >> 1, shA = (tid & 1) * 16;
  const int srB = tid >> 2, shB = (tid & 3) * 8;
  const int m = m0 + srA, b = m >> 11, s = m & 2047;

  {
    const int h = shA >> 6, d = shA & 63;
    long ao = ((long)((b * 16 + h) * 2048 + s)) * 64 + d;
    *(uint4*)&As[0][srA * 32 + shA]     = *(const uint4*)&AQ[ao];
    *(uint4*)&As[0][srA * 32 + shA + 8] = *(const uint4*)&AQ[ao + 8];
    long wo = (long)(n0 + srB) * 1024 + shB;
    *(uint4*)&Bs[0][srB * 32 + shB] = *(const uint4*)&WT[wo];
  }
  __syncthreads();

  int buf = 0;
  for (int kt = 0; kt < 1024; kt += 32) {
    const int nbuf = buf ^ 1;
    const bool pf = (kt + 32) < 1024;
    uint4 av0, av1, wv0;
    if (pf) {
      const int k = kt + 32 + shA, h = k >> 6, d = k & 63;
      long ao = ((long)((b * 16 + h) * 2048 + s)) * 64 + d;
      av0 = *(const uint4*)&AQ[ao];
      av1 = *(const uint4*)&AQ[ao + 8];
      long wo = (long)(n0 + srB) * 1024 + kt + 32 + shB;
      wv0 = *(const uint4*)&WT[wo];
    }

    bf16x8 af[4], bfr[2];
#pragma unroll
    for (int mq = 0; mq < 4; mq++)
      af[mq] = *(const bf16x8*)&As[buf][(mh * 64 + mq * 16 + l15) * 32 + quad * 8];
#pragma unroll
    for (int nq = 0; nq < 2; nq++)
      bfr[nq] = *(const bf16x8*)&Bs[buf][(nh * 32 + nq * 16 + l15) * 32 + quad * 8];
#pragma unroll
    for (int mq = 0; mq < 4; mq++)
#pragma unroll
      for (int nq = 0; nq < 2; nq++)
        acc[mq][nq] = __builtin_amdgcn_mfma_f32_16x16x32_bf16(af[mq], bfr[nq], acc[mq][nq], 0, 0, 0);

    if (pf) {
      *(uint4*)&As[nbuf][srA * 32 + shA]     = av0;
      *(uint4*)&As[nbuf][srA * 32 + shA + 8] = av1;
      *(uint4*)&Bs[nbuf][srB * 32 + shB]     = wv0;
    }
    __syncthreads();
    buf = nbuf;
  }

#pragma unroll
  for (int nq = 0; nq < 2; nq++) {
    int n = n0 + nh * 32 + nq * 16 + l15;
    float bv = bias[n];
#pragma unroll
    for (int mq = 0; mq < 4; mq++)
#pragma unroll
      for (int rr = 0; rr < 4; rr++) {
        int mm = m0 + mh * 64 + mq * 16 + quad * 4 + rr;
        Out[(long)mm * 1024 + n] = acc[mq][nq][rr] + bv;
      }
  }
}

extern "C" void kernel_launch(void* const* d_in, const int* in_sizes, int n_in,
                              void* d_out, int out_size, void* d_ws, size_t ws_size,
                              hipStream_t stream) {
  const float* X  = (const float*)d_in[0];
  const float* Wa = (const float*)d_in[1];
  const float* ba = (const float*)d_in[2];
  const float* Wp = (const float*)d_in[3];
  const float* bp = (const float*)d_in[4];
  const float* qg = (const float*)d_in[5];
  const float* qb = (const float*)d_in[6];
  const float* kg = (const float*)d_in[7];
  const float* kb = (const float*)d_in[8];

  const long per = 2L * 16 * 2048 * 64;     // 4,194,304 shorts
  unsigned short* ws  = (unsigned short*)d_ws;
  unsigned short* Qws = ws;
  unsigned short* Kws = Qws + per;
  unsigned short* Vt  = Kws + per;          // [bh][64 d][2048 s]

  const bool big = ws_size >= (size_t)(5L * per * 2);
  unsigned short *Xbf, *WaT, *WpT;
  if (big) {
    Xbf = Vt + per;
    WaT = Xbf + per;
    WpT = WaT + 3072L * 1024;
  } else {
    Xbf = Qws;  // unused
    WaT = Vt + per;
    WpT = WaT + 3072L * 1024;
  }

  prep_kernel<<<big ? 2048 : 1024, 256, 0, stream>>>(Wa, Wp, X, WaT, WpT, Xbf);
  qkvt_kernel<<<1024, 256, 0, stream>>>(X, Xbf, big ? 1 : 0, WaT, ba,
                                        qg, qb, kg, kb, Qws, Kws, Vt);
  attn_kernel<<<512, 512, 0, stream>>>(Qws, Kws, Vt);
  proj_kernel<<<dim3(16, 32), 256, 0, stream>>>(Qws, WpT, bp, (float*)d_out);
}